// Round 22
// baseline (166.335 us; speedup 1.0000x reference)
//
#include <hip/hip_runtime.h>
#include <hip/hip_bf16.h>

typedef __bf16 bf16;
typedef bf16 bf16x8 __attribute__((ext_vector_type(8)));
typedef bf16 bf16x4 __attribute__((ext_vector_type(4)));
typedef float f32x4 __attribute__((ext_vector_type(4)));
typedef float f32x16 __attribute__((ext_vector_type(16)));
typedef unsigned short ushortT;
typedef ushortT ushort8 __attribute__((ext_vector_type(8)));
typedef ushortT ushort4v __attribute__((ext_vector_type(4)));

#define DEV __device__ __forceinline__

constexpr int DMODEL = 1024;
constexpr int NH = 16;
constexpr int DK = 64;
constexpr int SEQ = 2048;
constexpr int BATCH = 4;
constexpr int MROWS = BATCH * SEQ;   // 8192
constexpr int KDIM = 1024;

#define GLOAD_LDS16(g, l) __builtin_amdgcn_global_load_lds( \
    (const __attribute__((address_space(1))) void*)(g), \
    (__attribute__((address_space(3))) void*)(l), 16, 0, 0)

#define PIPE_WAIT(N) do { \
    __builtin_amdgcn_sched_barrier(0); \
    asm volatile("s_waitcnt vmcnt(" #N ")" ::: "memory"); \
    __builtin_amdgcn_s_barrier(); \
    __builtin_amdgcn_sched_barrier(0); \
} while (0)

// ---------------- fused prep: X cvt | 4 weight cvts | RoPE table (one launch) ----
// blocks [0,4096): X; [4096,6144): weights (512 each); [6144,6400): rope table.
__global__ void prep(const float* __restrict__ X,
                     const float* __restrict__ s0, const float* __restrict__ s1,
                     const float* __restrict__ s2, const float* __restrict__ s3,
                     bf16* __restrict__ Xb,
                     bf16* __restrict__ d0, bf16* __restrict__ d1,
                     bf16* __restrict__ d2, bf16* __restrict__ d3,
                     float2* __restrict__ csT) {
    const int bid = (int)blockIdx.x;
    if (bid >= 6144) {
        int i = (bid - 6144) * 256 + threadIdx.x;   // [0, 2048*32)
        int p = i >> 5, k = i & 31;
        float inv = powf(10000.0f, -2.0f * (float)k / 64.0f);
        float ang = (float)p * inv;
        csT[i] = make_float2(cosf(ang), sinf(ang));
        return;
    }
    const float* s;
    bf16* d;
    int cb;
    if (bid < 4096)      { s = X;  d = Xb; cb = bid; }
    else {
        const int wsel = (bid - 4096) >> 9;         // 0..3
        cb = (bid - 4096) & 511;
        s = wsel == 0 ? s0 : wsel == 1 ? s1 : wsel == 2 ? s2 : s3;
        d = wsel == 0 ? d0 : wsel == 1 ? d1 : wsel == 2 ? d2 : d3;
    }
    int i = (cb * 256 + (int)threadIdx.x) * 8;
    float4 f0 = *reinterpret_cast<const float4*>(s + i);
    float4 f1 = *reinterpret_cast<const float4*>(s + i + 4);
    bf16x8 o;
    o[0] = (bf16)f0.x; o[1] = (bf16)f0.y; o[2] = (bf16)f0.z; o[3] = (bf16)f0.w;
    o[4] = (bf16)f1.x; o[5] = (bf16)f1.y; o[6] = (bf16)f1.z; o[7] = (bf16)f1.w;
    *reinterpret_cast<bf16x8*>(d + i) = o;
}

// ---------------- QKV GEMM (C^T = W X^T), 8-wave 128d x 256s tile, BK=64 ----------
__global__ __launch_bounds__(512, 2) void gemm_qkv(
    const bf16* __restrict__ Xb,
    const bf16* __restrict__ Wqb, const bf16* __restrict__ Wkb, const bf16* __restrict__ Wvb,
    bf16* __restrict__ Qb, bf16* __restrict__ Kb, bf16* __restrict__ Vt,
    const int* __restrict__ tokpos, const float2* __restrict__ csT)
{
    __shared__ bf16 Wl[3][128 * 64];   // 3 x 16KB
    __shared__ bf16 Xl[3][256 * 64];   // 3 x 32KB  (total 144KB)

    // xt-major bijective XCD swizzle: 768 blocks = 8 XCDs x (3 xt x 32 yt)
    const int bid = (int)blockIdx.x;
    const int xcd = bid & 7, idx = bid >> 3;   // idx 0..95
    const int xtile = xcd * 3 + idx % 3;       // 0..23
    const int ytile = idx / 3;                 // 0..31

    const int which = xtile >> 3;
    const bf16* Wmat = which == 0 ? Wqb : (which == 1 ? Wkb : Wvb);

    const int d0 = (xtile & 7) * 128;    // d-tile within 1024
    const int s0 = ytile * 256;          // token-row tile
    const int t = threadIdx.x;           // 0..511
    const int w = t >> 6, l = t & 63;
    const int wd = w >> 2, wq = w & 3;   // wave quadrant: d-half, s-quarter
    const int lm = l & 15, lg = l >> 4;
    const int lm7 = lm & 7;

    f32x4 acc[4][4] = {};   // [fi (d)][fj (s)]

    auto stageW = [&](int kt, int buf) {
#pragma unroll
        for (int j = 0; j < 2; ++j) {
            const int slot = w * 64 + j * 512 + l;   // per-lane, for source addr
            const int row = slot >> 3;
            const int col = ((slot & 7) ^ (row & 7)) * 8;
            GLOAD_LDS16(Wmat + (size_t)(d0 + row) * KDIM + kt + col,
                        &Wl[buf][(w * 64 + j * 512) * 8]);   // wave-uniform dest
        }
    };
    auto stageX = [&](int kt, int buf) {
#pragma unroll
        for (int j = 0; j < 4; ++j) {
            const int slot = w * 64 + j * 512 + l;
            const int row = slot >> 3;
            const int col = ((slot & 7) ^ (row & 7)) * 8;
            GLOAD_LDS16(Xb + (size_t)(s0 + row) * KDIM + kt + col,
                        &Xl[buf][(w * 64 + j * 512) * 8]);
        }
    };
    auto compute = [&](const bf16* Wb, const bf16* Xq) {
        bf16x8 wf[4][2], xf[4][2];
#pragma unroll
        for (int fi = 0; fi < 4; ++fi) {
            const int row = wd * 64 + fi * 16 + lm;
#pragma unroll
            for (int kk = 0; kk < 2; ++kk)
                wf[fi][kk] = *reinterpret_cast<const bf16x8*>(
                    Wb + row * 64 + (((kk * 4 + lg) ^ lm7) * 8));
        }
#pragma unroll
        for (int fj = 0; fj < 4; ++fj) {
            const int row = wq * 64 + fj * 16 + lm;
#pragma unroll
            for (int kk = 0; kk < 2; ++kk)
                xf[fj][kk] = *reinterpret_cast<const bf16x8*>(
                    Xq + row * 64 + (((kk * 4 + lg) ^ lm7) * 8));
        }
        __builtin_amdgcn_s_setprio(1);
#pragma unroll
        for (int kk = 0; kk < 2; ++kk)
#pragma unroll
            for (int fi = 0; fi < 4; ++fi)
#pragma unroll
                for (int fj = 0; fj < 4; ++fj)
                    acc[fi][fj] = __builtin_amdgcn_mfma_f32_16x16x32_bf16(
                        wf[fi][kk], xf[fj][kk], acc[fi][fj], 0, 0, 0);
        __builtin_amdgcn_s_setprio(0);
    };

    stageW(0, 0);
    stageX(0, 0);
    stageW(64, 1);
    stageX(64, 1);
    PIPE_WAIT(6);   // tile0 landed; tile1 in flight

#pragma unroll
    for (int tt = 0; tt < 16; ++tt) {
        if (tt + 2 < 16) {
            stageW((tt + 2) * 64, (tt + 2) % 3);
            stageX((tt + 2) * 64, (tt + 2) % 3);
        }
        compute(&Wl[tt % 3][0], &Xl[tt % 3][0]);
        if (tt < 14)       PIPE_WAIT(6);   // tile tt+1 landed; tt+2 in flight
        else if (tt == 14) PIPE_WAIT(0);   // tile 15 landed
        // tt == 15: fall through to epilogue
    }

    const int h = ((xtile & 7) << 1) + wd;   // head index

    if (which < 2) {
        // Q/K: lane-local RoPE + vectorized scatter to [B,H,S,DK]
        bf16* Out = which == 0 ? Qb : Kb;
#pragma unroll
        for (int fj = 0; fj < 4; ++fj) {
            const int rowg = s0 + wq * 64 + fj * 16 + lm;  // global token row
            const int b = rowg >> 11, ss = rowg & 2047;
            const size_t obase = ((size_t)(b * NH + h) * SEQ + ss) * DK;
            const int p = tokpos[rowg];
#pragma unroll
            for (int fi = 0; fi < 4; ++fi) {
                const int dloc = fi * 16 + lg * 4;   // within-head d, multiple of 4
                f32x4 a = acc[fi][fj];
                bf16x4 v4;
                const int k2 = dloc >> 1;
                float2 cs0 = csT[p * 32 + k2];
                float2 cs1 = csT[p * 32 + k2 + 1];
                v4[0] = (bf16)(a[0] * cs0.x - a[1] * cs0.y);
                v4[1] = (bf16)(a[0] * cs0.y + a[1] * cs0.x);
                v4[2] = (bf16)(a[2] * cs1.x - a[3] * cs1.y);
                v4[3] = (bf16)(a[2] * cs1.y + a[3] * cs1.x);
                *reinterpret_cast<bf16x4*>(Out + obase + dloc) = v4;
            }
        }
    } else {
        // V: per-wave LDS transpose + sigma quad-swap -> Vt[B,H,DK,S] directly.
        ushortT* Tw = reinterpret_cast<ushortT*>(&Xl[1][0]) + w * 4096;
#pragma unroll
        for (int fj = 0; fj < 4; ++fj) {
            const int s_ = fj * 16 + lm;
            const int slotb = s_ >> 2, sub = s_ & 3;
#pragma unroll
            for (int fi = 0; fi < 4; ++fi) {
#pragma unroll
                for (int e = 0; e < 4; ++e) {
                    const int d_ = fi * 16 + lg * 4 + e;
                    Tw[d_ * 64 + ((slotb ^ (d_ & 15)) * 4) + sub] =
                        __builtin_bit_cast(ushortT, (bf16)acc[fi][fj][e]);
                }
            }
        }
        asm volatile("s_waitcnt lgkmcnt(0)" ::: "memory");
        __builtin_amdgcn_sched_barrier(0);
        const int d_ = l;
        const int rowg0 = s0 + wq * 64;
        const int b2 = rowg0 >> 11, ss0 = rowg0 & 2047;
        ushortT* dst = reinterpret_cast<ushortT*>(Vt) +
                       ((size_t)(b2 * NH + h) * DK + d_) * SEQ + ss0;
        const ushortT* Twr = reinterpret_cast<const ushortT*>(&Xl[1][0]) + w * 4096 + d_ * 64;
        const int dx = d_ & 15;
#pragma unroll
        for (int g = 0; g < 4; ++g) {
            ushort4v A  = *reinterpret_cast<const ushort4v*>(Twr + ((4 * g + 0) ^ dx) * 4);
            ushort4v Bq = *reinterpret_cast<const ushort4v*>(Twr + ((4 * g + 1) ^ dx) * 4);
            ushort4v C  = *reinterpret_cast<const ushort4v*>(Twr + ((4 * g + 2) ^ dx) * 4);
            ushort4v D  = *reinterpret_cast<const ushort4v*>(Twr + ((4 * g + 3) ^ dx) * 4);
            ushort8 o0, o1;
#pragma unroll
            for (int i = 0; i < 4; ++i) {
                o0[i] = A[i];  o0[4 + i] = C[i];
                o1[i] = Bq[i]; o1[4 + i] = D[i];
            }
            *reinterpret_cast<ushort8*>(dst + g * 16) = o0;
            *reinterpret_cast<ushort8*>(dst + g * 16 + 8) = o1;
        }
    }
}

// ---------------- flash attention (causal), LDS-staged K/V, 32x32 MFMA ----------------
// Depth-2 counted-vmcnt pipeline; T5 setprio around both MFMA clusters.
constexpr float CL = 0.18033688011112042f;  // 0.125 * log2(e)
constexpr float THR = 64.0f;                // defer-max threshold (raw units; 8 post-scale)

template<int MODE>  // 0: chunks 0+1 unmasked; 1: chunks 0+1 masked; 2: chunk0 only, masked
DEV void tileproc(const bf16* __restrict__ Klb, const bf16* __restrict__ Vlb,
                  int kv0, int q_abs, int ql, int hi, int swq,
                  const bf16x8 qb[4], f32x16 o[2], float& lsum, float& mrow)
{
    f32x16 s0 = {}, s1 = {};
    __builtin_amdgcn_s_setprio(1);
#pragma unroll
    for (int sl = 0; sl < 4; ++sl) {
        bf16x8 k0 = *reinterpret_cast<const bf16x8*>(&Klb[ql * 64 + (((sl * 2 + hi) ^ swq) * 8)]);
        s0 = __builtin_amdgcn_mfma_f32_32x32x16_bf16(k0, qb[sl], s0, 0, 0, 0);
        if (MODE != 2) {
            bf16x8 k1 = *reinterpret_cast<const bf16x8*>(&Klb[(32 + ql) * 64 + (((sl * 2 + hi) ^ swq) * 8)]);
            s1 = __builtin_amdgcn_mfma_f32_32x32x16_bf16(k1, qb[sl], s1, 0, 0, 0);
        }
    }
    __builtin_amdgcn_s_setprio(0);

    if (MODE >= 1) {
#pragma unroll
        for (int r = 0; r < 16; ++r) {
            const int kvl = (r & 3) + 8 * (r >> 2) + 4 * hi;
            if (kv0 + kvl > q_abs) s0[r] = -1e30f;
            if (MODE == 1 && kv0 + 32 + kvl > q_abs) s1[r] = -1e30f;
        }
    }

    f32x16 mm = s0;
    if (MODE != 2) {
#pragma unroll
        for (int r = 0; r < 16; ++r) mm[r] = fmaxf(mm[r], s1[r]);
    }
    float m0 = fmaxf(fmaxf(mm[0], mm[1]), fmaxf(mm[2], mm[3]));
    float m1 = fmaxf(fmaxf(mm[4], mm[5]), fmaxf(mm[6], mm[7]));
    float m2 = fmaxf(fmaxf(mm[8], mm[9]), fmaxf(mm[10], mm[11]));
    float m3 = fmaxf(fmaxf(mm[12], mm[13]), fmaxf(mm[14], mm[15]));
    float pmax = fmaxf(fmaxf(m0, m1), fmaxf(m2, m3));
    pmax = fmaxf(pmax, __shfl_xor(pmax, 32));

    if (!__all(pmax <= mrow + THR)) {
        const float mnew = fmaxf(mrow, pmax);
        const float alpha = __builtin_amdgcn_exp2f((mrow - mnew) * CL);
        mrow = mnew;
        lsum *= alpha;
        o[0] *= alpha;
        o[1] *= alpha;
    }

#pragma unroll
    for (int r = 0; r < 16; ++r) {
        s0[r] = __builtin_amdgcn_exp2f((s0[r] - mrow) * CL);
        if (MODE != 2) s1[r] = __builtin_amdgcn_exp2f((s1[r] - mrow) * CL);
    }
    {
        float a0 = (s0[0] + s0[1]) + (s0[2] + s0[3]);
        float a1 = (s0[4] + s0[5]) + (s0[6] + s0[7]);
        float a2 = (s0[8] + s0[9]) + (s0[10] + s0[11]);
        float a3 = (s0[12] + s0[13]) + (s0[14] + s0[15]);
        float ps = (a0 + a1) + (a2 + a3);
        if (MODE != 2) {
            float b0 = (s1[0] + s1[1]) + (s1[2] + s1[3]);
            float b1 = (s1[4] + s1[5]) + (s1[6] + s1[7]);
            float b2 = (s1[8] + s1[9]) + (s1[10] + s1[11]);
            float b3 = (s1[12] + s1[13]) + (s1[14] + s1[15]);
            ps += (b0 + b1) + (b2 + b3);
        }
        lsum += ps;
    }

#pragma unroll
    for (int c = 0; c < (MODE == 2 ? 1 : 2); ++c) {
#pragma unroll
        for (int u2 = 0; u2 < 2; ++u2) {
            const int u = c * 2 + u2;
            bf16x8 pb;
#pragma unroll
            for (int j = 0; j < 8; ++j) pb[j] = (bf16)(c ? s1[u2 * 8 + j] : s0[u2 * 8 + j]);
            __builtin_amdgcn_s_setprio(1);
#pragma unroll
            for (int dt = 0; dt < 2; ++dt) {
                bf16x8 va = *reinterpret_cast<const bf16x8*>(
                    &Vlb[(dt * 32 + ql) * 64 + (((u * 2 + hi) ^ swq) * 8)]);
                o[dt] = __builtin_amdgcn_mfma_f32_32x32x16_bf16(va, pb, o[dt], 0, 0, 0);
            }
            __builtin_amdgcn_s_setprio(0);
        }
    }
}

__global__ __launch_bounds__(256, 3) void attn(
    const bf16* __restrict__ Qb, const bf16* __restrict__ Kb, const bf16* __restrict__ Vt,
    bf16* __restrict__ Ab)
{
    __shared__ bf16 Kl[3][64 * 64];
    __shared__ bf16 Vl[3][64 * 64];

    const int bh = blockIdx.x;
    const int qt = (int)gridDim.y - 1 - (int)blockIdx.y;   // longest tiles launch first (LPT)
    const int t = threadIdx.x, w = t >> 6, l = t & 63;
    const int ql = l & 31, hi = l >> 5;
    const int q0 = qt * 128 + w * 32;
    const bf16* Qh = Qb + (size_t)bh * SEQ * DK;
    const bf16* Kh = Kb + (size_t)bh * SEQ * DK;
    const bf16* Vh = Vt + (size_t)bh * DK * SEQ;

    const int lr = l >> 3, slot = l & 7;
    const int sw8 = ((slot ^ lr) * 8);
    const int r0 = w * 8 + lr;

    auto stage = [&](int tile, int buf) {
        const int kv0 = tile * 64;
        GLOAD_LDS16(Kh + (size_t)(kv0 + r0) * DK + sw8,       &Kl[buf][w * 512]);
        GLOAD_LDS16(Kh + (size_t)(kv0 + 32 + r0) * DK + sw8,  &Kl[buf][2048 + w * 512]);
        GLOAD_LDS16(Vh + (size_t)r0 * SEQ + kv0 + sw8,        &Vl[buf][w * 512]);
        GLOAD_LDS16(Vh + (size_t)(32 + r0) * SEQ + kv0 + sw8, &Vl[buf][2048 + w * 512]);
    };

    bf16x8 qb[4];
#pragma unroll
    for (int sl = 0; sl < 4; ++sl)
        qb[sl] = *reinterpret_cast<const bf16x8*>(Qh + (size_t)(q0 + ql) * DK + sl * 16 + hi * 8);

    f32x16 o[2] = {};
    float lsum = 0.0f;
    float mrow = -1e30f;
    const int q_abs = q0 + ql;
    const int swq = ql & 7;

    const int ntile = 2 * qt + 2;   // always >= 2
    stage(0, 0);
    stage(1, 1);
    PIPE_WAIT(4);                   // tile0 landed; tile1 in flight
    for (int tt = 0; tt < ntile; ++tt) {
        if (tt + 2 < ntile) stage(tt + 2, (tt + 2) % 3);
        const int kv0 = tt * 64;
        const bf16* Klb = &Kl[tt % 3][0];
        const bf16* Vlb = &Vl[tt % 3][0];
        if (tt < 2 * qt) {
            tileproc<0>(Klb, Vlb, kv0, q_abs, ql, hi, swq, qb, o, lsum, mrow);
        } else {
            const bool a0 = kv0 <= q0 + 31;
            const bool a1 = kv0 + 32 <= q0 + 31;
            if (a1)      tileproc<1>(Klb, Vlb, kv0, q_abs, ql, hi, swq, qb, o, lsum, mrow);
            else if (a0) tileproc<2>(Klb, Vlb, kv0, q_abs, ql, hi, swq, qb, o, lsum, mrow);
        }
        if (tt + 1 < ntile) {
            if (tt + 2 < ntile) PIPE_WAIT(4);   // t+1 landed; t+2 in flight
            else               PIPE_WAIT(0);    // only t+1 outstanding
        }
        // tt == ntile-1: fall through to epilogue
    }

    const float rs = lsum + __shfl_xor(lsum, 32);
    const float rinv = 1.0f / rs;

    const int b = bh >> 4, h = bh & 15;
    const int q = q0 + ql;
    const size_t rowbase = ((size_t)(b * SEQ + q)) * DMODEL + h * 64;
#pragma unroll
    for (int dt = 0; dt < 2; ++dt)
#pragma unroll
        for (int g = 0; g < 4; ++g) {
            bf16x4 v4;
#pragma unroll
            for (int e = 0; e < 4; ++e) v4[e] = (bf16)(o[dt][4 * g + e] * rinv);
            *reinterpret_cast<bf16x4*>(Ab + rowbase + dt * 32 + 8 * g + 4 * hi) = v4;
        }
}

// ---------------- output GEMM (C^T = Wo Ab^T), 8-wave depth-2 pipeline (R13) ------
__global__ __launch_bounds__(512, 2) void gemm_out(
    const bf16* __restrict__ Ab, const bf16* __restrict__ Wob, float* __restrict__ Out)
{
    __shared__ bf16 Wl[3][128 * 64];
    __shared__ bf16 Xl[3][256 * 64];

    // T1 bijective swizzle: 256 blocks = 8 XCDs x 32
    const int bid = (int)blockIdx.x;
    const int swz = (bid & 7) * 32 + (bid >> 3);
    const int ytile = swz >> 3;          // s-tile 0..31
    const int xtile = swz & 7;           // n-tile 0..7

    const int n0 = xtile * 128;          // output-channel tile
    const int s0 = ytile * 256;          // token-row tile
    const int t = threadIdx.x;
    const int w = t >> 6, l = t & 63;
    const int wd = w >> 2, wq = w & 3;
    const int lm = l & 15, lg = l >> 4;
    const int lm7 = lm & 7;

    f32x4 acc[4][4] = {};   // [fi (n)][fj (s)]

    auto stageW = [&](int kt, int buf) {
#pragma unroll
        for (int j = 0; j < 2; ++j) {
            const int slot = w * 64 + j * 512 + l;
            const int row = slot >> 3;
            const int col = ((slot & 7) ^ (row & 7)) * 8;
            GLOAD_LDS16(Wob + (size_t)(n0 + row) * KDIM + kt + col,
                        &Wl[buf][(w * 64 + j * 512) * 8]);
        }
    };
    auto stageX = [&](int kt, int buf) {
#pragma unroll
        for (int j = 0; j < 4; ++j) {
            const int slot = w * 64 + j * 512 + l;
            const int row = slot >> 3;
            const int col = ((slot & 7) ^ (row & 7)) * 8;
            GLOAD_LDS16(Ab + (size_t)(s0 + row) * KDIM + kt + col,
                        &Xl[buf][(w * 64 + j * 512) * 8]);
        }
    };
    auto compute = [&](const bf16* Wb, const bf16* Xq) {
        bf16x8 wf[4][2], xf[4][2];
#pragma unroll
        for (int fi = 0; fi < 4; ++fi) {
            const int row = wd * 64 + fi * 16 + lm;
#pragma unroll
            for (int kk = 0; kk < 2; ++kk)
                wf[fi][kk] = *reinterpret_cast<const bf16x8*>(
                    Wb + row * 64 + (((kk * 4 + lg) ^ lm7) * 8));
        }
#pragma unroll
        for (int fj = 0; fj < 4; ++fj) {
            const int row = wq * 64 + fj * 16 + lm;
#pragma unroll
            for (int kk = 0; kk < 2; ++kk)
                xf[fj][kk] = *reinterpret_cast<const bf16x8*>(
                    Xq + row * 64 + (((kk * 4 + lg) ^ lm7) * 8));
        }
        __builtin_amdgcn_s_setprio(1);
#pragma unroll
        for (int kk = 0; kk < 2; ++kk)
#pragma unroll
            for (int fi = 0; fi < 4; ++fi)
#pragma unroll
                for (int fj = 0; fj < 4; ++fj)
                    acc[fi][fj] = __builtin_amdgcn_mfma_f32_16x16x32_bf16(
                        wf[fi][kk], xf[fj][kk], acc[fi][fj], 0, 0, 0);
        __builtin_amdgcn_s_setprio(0);
    };

    stageW(0, 0);
    stageX(0, 0);
    stageW(64, 1);
    stageX(64, 1);
    PIPE_WAIT(6);

#pragma unroll
    for (int tt = 0; tt < 16; ++tt) {
        if (tt + 2 < 16) {
            stageW((tt + 2) * 64, (tt + 2) % 3);
            stageX((tt + 2) * 64, (tt + 2) % 3);
        }
        compute(&Wl[tt % 3][0], &Xl[tt % 3][0]);
        if (tt < 14)       PIPE_WAIT(6);
        else if (tt == 14) PIPE_WAIT(0);
    }

#pragma unroll
    for (int fj = 0; fj < 4; ++fj) {
        const int rowg = s0 + wq * 64 + fj * 16 + lm;
#pragma unroll
        for (int fi = 0; fi < 4; ++fi) {
            const int ncol = n0 + wd * 64 + fi * 16 + lg * 4;
            *reinterpret_cast<f32x4*>(Out + (size_t)rowg * DMODEL + ncol) = acc[fi][fj];
        }
    }
}

// ---------------- launch ----------------
extern "C" void kernel_launch(void* const* d_in, const int* in_sizes, int n_in,
                              void* d_out, int out_size, void* d_ws, size_t ws_size,
                              hipStream_t stream) {
    const float* X  = (const float*)d_in[0];
    const int* tokpos = (const int*)d_in[1];
    const float* Wq = (const float*)d_in[2];
    const float* Wk = (const float*)d_in[3];
    const float* Wv = (const float*)d_in[4];
    const float* Wo = (const float*)d_in[5];

    char* ws = (char*)d_ws;
    bf16* Xb  = (bf16*)(ws + 0);            // 16 MB
    bf16* Wqb = (bf16*)(ws + 16777216);     // 2 MB
    bf16* Wkb = (bf16*)(ws + 18874368);
    bf16* Wvb = (bf16*)(ws + 20971520);
    bf16* Wob = (bf16*)(ws + 23068672);
    float2* csT = (float2*)(ws + 25165824); // 512 KB interleaved (cos,sin)
    bf16* Qb = (bf16*)(ws + 25690112);      // 16 MB
    bf16* Kb = (bf16*)(ws + 42467328);
    bf16* Vt = (bf16*)(ws + 59244544);      // 16 MB (V^T, sigma-permuted)
    bf16* Ab = (bf16*)(ws + 76021760);      // 16 MB

    prep<<<6400, 256, 0, stream>>>(X, Wq, Wk, Wv, Wo, Xb, Wqb, Wkb, Wvb, Wob, csT);

    gemm_qkv<<<dim3(768), 512, 0, stream>>>(
        Xb, Wqb, Wkb, Wvb, Qb, Kb, Vt, tokpos, csT);

    attn<<<dim3(BATCH * NH, SEQ / 128), 256, 0, stream>>>(Qb, Kb, Vt, Ab);

    gemm_out<<<dim3(256), 512, 0, stream>>>(Ab, Wob, (float*)d_out);
}

// Round 23
// 165.731 us; speedup vs baseline: 1.0036x; 1.0036x over previous
//
#include <hip/hip_runtime.h>
#include <hip/hip_bf16.h>

typedef __bf16 bf16;
typedef bf16 bf16x8 __attribute__((ext_vector_type(8)));
typedef bf16 bf16x4 __attribute__((ext_vector_type(4)));
typedef float f32x4 __attribute__((ext_vector_type(4)));
typedef float f32x16 __attribute__((ext_vector_type(16)));
typedef unsigned short ushortT;
typedef ushortT ushort8 __attribute__((ext_vector_type(8)));
typedef ushortT ushort4v __attribute__((ext_vector_type(4)));

#define DEV __device__ __forceinline__

constexpr int DMODEL = 1024;
constexpr int NH = 16;
constexpr int DK = 64;
constexpr int SEQ = 2048;
constexpr int BATCH = 4;
constexpr int MROWS = BATCH * SEQ;   // 8192
constexpr int KDIM = 1024;

#define GLOAD_LDS16(g, l) __builtin_amdgcn_global_load_lds( \
    (const __attribute__((address_space(1))) void*)(g), \
    (__attribute__((address_space(3))) void*)(l), 16, 0, 0)

#define PIPE_WAIT(N) do { \
    __builtin_amdgcn_sched_barrier(0); \
    asm volatile("s_waitcnt vmcnt(" #N ")" ::: "memory"); \
    __builtin_amdgcn_s_barrier(); \
    __builtin_amdgcn_sched_barrier(0); \
} while (0)

// ---------------- fused prep: X cvt | 4 weight cvts | RoPE table (one launch) ----
// blocks [0,4096): X; [4096,6144): weights (512 each); [6144,6400): rope table.
__global__ void prep(const float* __restrict__ X,
                     const float* __restrict__ s0, const float* __restrict__ s1,
                     const float* __restrict__ s2, const float* __restrict__ s3,
                     bf16* __restrict__ Xb,
                     bf16* __restrict__ d0, bf16* __restrict__ d1,
                     bf16* __restrict__ d2, bf16* __restrict__ d3,
                     float2* __restrict__ csT) {
    const int bid = (int)blockIdx.x;
    if (bid >= 6144) {
        int i = (bid - 6144) * 256 + threadIdx.x;   // [0, 2048*32)
        int p = i >> 5, k = i & 31;
        float inv = powf(10000.0f, -2.0f * (float)k / 64.0f);
        float ang = (float)p * inv;
        csT[i] = make_float2(cosf(ang), sinf(ang));
        return;
    }
    const float* s;
    bf16* d;
    int cb;
    if (bid < 4096)      { s = X;  d = Xb; cb = bid; }
    else {
        const int wsel = (bid - 4096) >> 9;         // 0..3
        cb = (bid - 4096) & 511;
        s = wsel == 0 ? s0 : wsel == 1 ? s1 : wsel == 2 ? s2 : s3;
        d = wsel == 0 ? d0 : wsel == 1 ? d1 : wsel == 2 ? d2 : d3;
    }
    int i = (cb * 256 + (int)threadIdx.x) * 8;
    float4 f0 = *reinterpret_cast<const float4*>(s + i);
    float4 f1 = *reinterpret_cast<const float4*>(s + i + 4);
    bf16x8 o;
    o[0] = (bf16)f0.x; o[1] = (bf16)f0.y; o[2] = (bf16)f0.z; o[3] = (bf16)f0.w;
    o[4] = (bf16)f1.x; o[5] = (bf16)f1.y; o[6] = (bf16)f1.z; o[7] = (bf16)f1.w;
    *reinterpret_cast<bf16x8*>(d + i) = o;
}

// ---------------- QKV GEMM (C^T = W X^T), 8-wave 128d x 256s tile, BK=64 ----------
__global__ __launch_bounds__(512, 2) void gemm_qkv(
    const bf16* __restrict__ Xb,
    const bf16* __restrict__ Wqb, const bf16* __restrict__ Wkb, const bf16* __restrict__ Wvb,
    bf16* __restrict__ Qb, bf16* __restrict__ Kb, bf16* __restrict__ Vt,
    const int* __restrict__ tokpos, const float2* __restrict__ csT)
{
    __shared__ bf16 Wl[3][128 * 64];   // 3 x 16KB
    __shared__ bf16 Xl[3][256 * 64];   // 3 x 32KB  (total 144KB)

    // xt-major bijective XCD swizzle: 768 blocks = 8 XCDs x (3 xt x 32 yt)
    const int bid = (int)blockIdx.x;
    const int xcd = bid & 7, idx = bid >> 3;   // idx 0..95
    const int xtile = xcd * 3 + idx % 3;       // 0..23
    const int ytile = idx / 3;                 // 0..31

    const int which = xtile >> 3;
    const bf16* Wmat = which == 0 ? Wqb : (which == 1 ? Wkb : Wvb);

    const int d0 = (xtile & 7) * 128;    // d-tile within 1024
    const int s0 = ytile * 256;          // token-row tile
    const int t = threadIdx.x;           // 0..511
    const int w = t >> 6, l = t & 63;
    const int wd = w >> 2, wq = w & 3;   // wave quadrant: d-half, s-quarter
    const int lm = l & 15, lg = l >> 4;
    const int lm7 = lm & 7;

    f32x4 acc[4][4] = {};   // [fi (d)][fj (s)]

    auto stageW = [&](int kt, int buf) {
#pragma unroll
        for (int j = 0; j < 2; ++j) {
            const int slot = w * 64 + j * 512 + l;   // per-lane, for source addr
            const int row = slot >> 3;
            const int col = ((slot & 7) ^ (row & 7)) * 8;
            GLOAD_LDS16(Wmat + (size_t)(d0 + row) * KDIM + kt + col,
                        &Wl[buf][(w * 64 + j * 512) * 8]);   // wave-uniform dest
        }
    };
    auto stageX = [&](int kt, int buf) {
#pragma unroll
        for (int j = 0; j < 4; ++j) {
            const int slot = w * 64 + j * 512 + l;
            const int row = slot >> 3;
            const int col = ((slot & 7) ^ (row & 7)) * 8;
            GLOAD_LDS16(Xb + (size_t)(s0 + row) * KDIM + kt + col,
                        &Xl[buf][(w * 64 + j * 512) * 8]);
        }
    };
    auto compute = [&](const bf16* Wb, const bf16* Xq) {
        bf16x8 wf[4][2], xf[4][2];
#pragma unroll
        for (int fi = 0; fi < 4; ++fi) {
            const int row = wd * 64 + fi * 16 + lm;
#pragma unroll
            for (int kk = 0; kk < 2; ++kk)
                wf[fi][kk] = *reinterpret_cast<const bf16x8*>(
                    Wb + row * 64 + (((kk * 4 + lg) ^ lm7) * 8));
        }
#pragma unroll
        for (int fj = 0; fj < 4; ++fj) {
            const int row = wq * 64 + fj * 16 + lm;
#pragma unroll
            for (int kk = 0; kk < 2; ++kk)
                xf[fj][kk] = *reinterpret_cast<const bf16x8*>(
                    Xq + row * 64 + (((kk * 4 + lg) ^ lm7) * 8));
        }
        __builtin_amdgcn_s_setprio(1);
#pragma unroll
        for (int kk = 0; kk < 2; ++kk)
#pragma unroll
            for (int fi = 0; fi < 4; ++fi)
#pragma unroll
                for (int fj = 0; fj < 4; ++fj)
                    acc[fi][fj] = __builtin_amdgcn_mfma_f32_16x16x32_bf16(
                        wf[fi][kk], xf[fj][kk], acc[fi][fj], 0, 0, 0);
        __builtin_amdgcn_s_setprio(0);
    };

    stageW(0, 0);
    stageX(0, 0);
    stageW(64, 1);
    stageX(64, 1);
    PIPE_WAIT(6);   // tile0 landed; tile1 in flight

#pragma unroll
    for (int tt = 0; tt < 16; ++tt) {
        if (tt + 2 < 16) {
            stageW((tt + 2) * 64, (tt + 2) % 3);
            stageX((tt + 2) * 64, (tt + 2) % 3);
        }
        compute(&Wl[tt % 3][0], &Xl[tt % 3][0]);
        if (tt < 14)       PIPE_WAIT(6);   // tile tt+1 landed; tt+2 in flight
        else if (tt == 14) PIPE_WAIT(0);   // tile 15 landed
        // tt == 15: fall through to epilogue
    }

    const int h = ((xtile & 7) << 1) + wd;   // head index

    if (which < 2) {
        // Q/K: lane-local RoPE + vectorized scatter to [B,H,S,DK]
        bf16* Out = which == 0 ? Qb : Kb;
#pragma unroll
        for (int fj = 0; fj < 4; ++fj) {
            const int rowg = s0 + wq * 64 + fj * 16 + lm;  // global token row
            const int b = rowg >> 11, ss = rowg & 2047;
            const size_t obase = ((size_t)(b * NH + h) * SEQ + ss) * DK;
            const int p = tokpos[rowg];
#pragma unroll
            for (int fi = 0; fi < 4; ++fi) {
                const int dloc = fi * 16 + lg * 4;   // within-head d, multiple of 4
                f32x4 a = acc[fi][fj];
                bf16x4 v4;
                const int k2 = dloc >> 1;
                float2 cs0 = csT[p * 32 + k2];
                float2 cs1 = csT[p * 32 + k2 + 1];
                v4[0] = (bf16)(a[0] * cs0.x - a[1] * cs0.y);
                v4[1] = (bf16)(a[0] * cs0.y + a[1] * cs0.x);
                v4[2] = (bf16)(a[2] * cs1.x - a[3] * cs1.y);
                v4[3] = (bf16)(a[2] * cs1.y + a[3] * cs1.x);
                *reinterpret_cast<bf16x4*>(Out + obase + dloc) = v4;
            }
        }
    } else {
        // V: per-wave LDS transpose + sigma quad-swap -> Vt[B,H,DK,S] directly.
        ushortT* Tw = reinterpret_cast<ushortT*>(&Xl[1][0]) + w * 4096;
#pragma unroll
        for (int fj = 0; fj < 4; ++fj) {
            const int s_ = fj * 16 + lm;
            const int slotb = s_ >> 2, sub = s_ & 3;
#pragma unroll
            for (int fi = 0; fi < 4; ++fi) {
#pragma unroll
                for (int e = 0; e < 4; ++e) {
                    const int d_ = fi * 16 + lg * 4 + e;
                    Tw[d_ * 64 + ((slotb ^ (d_ & 15)) * 4) + sub] =
                        __builtin_bit_cast(ushortT, (bf16)acc[fi][fj][e]);
                }
            }
        }
        asm volatile("s_waitcnt lgkmcnt(0)" ::: "memory");
        __builtin_amdgcn_sched_barrier(0);
        const int d_ = l;
        const int rowg0 = s0 + wq * 64;
        const int b2 = rowg0 >> 11, ss0 = rowg0 & 2047;
        ushortT* dst = reinterpret_cast<ushortT*>(Vt) +
                       ((size_t)(b2 * NH + h) * DK + d_) * SEQ + ss0;
        const ushortT* Twr = reinterpret_cast<const ushortT*>(&Xl[1][0]) + w * 4096 + d_ * 64;
        const int dx = d_ & 15;
#pragma unroll
        for (int g = 0; g < 4; ++g) {
            ushort4v A  = *reinterpret_cast<const ushort4v*>(Twr + ((4 * g + 0) ^ dx) * 4);
            ushort4v Bq = *reinterpret_cast<const ushort4v*>(Twr + ((4 * g + 1) ^ dx) * 4);
            ushort4v C  = *reinterpret_cast<const ushort4v*>(Twr + ((4 * g + 2) ^ dx) * 4);
            ushort4v D  = *reinterpret_cast<const ushort4v*>(Twr + ((4 * g + 3) ^ dx) * 4);
            ushort8 o0, o1;
#pragma unroll
            for (int i = 0; i < 4; ++i) {
                o0[i] = A[i];  o0[4 + i] = C[i];
                o1[i] = Bq[i]; o1[4 + i] = D[i];
            }
            *reinterpret_cast<ushort8*>(dst + g * 16) = o0;
            *reinterpret_cast<ushort8*>(dst + g * 16 + 8) = o1;
        }
    }
}

// ---------------- flash attention (causal), LDS-staged K/V, 32x32 MFMA ----------------
// Depth-2 counted-vmcnt pipeline: 3 K/V buffers, stage t+2 before compute(t),
// tile-end vmcnt(4)+barrier — no full drain mid-loop.
constexpr float CL = 0.18033688011112042f;  // 0.125 * log2(e)
constexpr float THR = 64.0f;                // defer-max threshold (raw units; 8 post-scale)

template<int MODE>  // 0: chunks 0+1 unmasked; 1: chunks 0+1 masked; 2: chunk0 only, masked
DEV void tileproc(const bf16* __restrict__ Klb, const bf16* __restrict__ Vlb,
                  int kv0, int q_abs, int ql, int hi, int swq,
                  const bf16x8 qb[4], f32x16 o[2], float& lsum, float& mrow)
{
    f32x16 s0 = {}, s1 = {};
#pragma unroll
    for (int sl = 0; sl < 4; ++sl) {
        bf16x8 k0 = *reinterpret_cast<const bf16x8*>(&Klb[ql * 64 + (((sl * 2 + hi) ^ swq) * 8)]);
        s0 = __builtin_amdgcn_mfma_f32_32x32x16_bf16(k0, qb[sl], s0, 0, 0, 0);
        if (MODE != 2) {
            bf16x8 k1 = *reinterpret_cast<const bf16x8*>(&Klb[(32 + ql) * 64 + (((sl * 2 + hi) ^ swq) * 8)]);
            s1 = __builtin_amdgcn_mfma_f32_32x32x16_bf16(k1, qb[sl], s1, 0, 0, 0);
        }
    }

    if (MODE >= 1) {
#pragma unroll
        for (int r = 0; r < 16; ++r) {
            const int kvl = (r & 3) + 8 * (r >> 2) + 4 * hi;
            if (kv0 + kvl > q_abs) s0[r] = -1e30f;
            if (MODE == 1 && kv0 + 32 + kvl > q_abs) s1[r] = -1e30f;
        }
    }

    f32x16 mm = s0;
    if (MODE != 2) {
#pragma unroll
        for (int r = 0; r < 16; ++r) mm[r] = fmaxf(mm[r], s1[r]);
    }
    float m0 = fmaxf(fmaxf(mm[0], mm[1]), fmaxf(mm[2], mm[3]));
    float m1 = fmaxf(fmaxf(mm[4], mm[5]), fmaxf(mm[6], mm[7]));
    float m2 = fmaxf(fmaxf(mm[8], mm[9]), fmaxf(mm[10], mm[11]));
    float m3 = fmaxf(fmaxf(mm[12], mm[13]), fmaxf(mm[14], mm[15]));
    float pmax = fmaxf(fmaxf(m0, m1), fmaxf(m2, m3));
    pmax = fmaxf(pmax, __shfl_xor(pmax, 32));

    if (!__all(pmax <= mrow + THR)) {
        const float mnew = fmaxf(mrow, pmax);
        const float alpha = __builtin_amdgcn_exp2f((mrow - mnew) * CL);
        mrow = mnew;
        lsum *= alpha;
        o[0] *= alpha;
        o[1] *= alpha;
    }

#pragma unroll
    for (int r = 0; r < 16; ++r) {
        s0[r] = __builtin_amdgcn_exp2f((s0[r] - mrow) * CL);
        if (MODE != 2) s1[r] = __builtin_amdgcn_exp2f((s1[r] - mrow) * CL);
    }
    {
        float a0 = (s0[0] + s0[1]) + (s0[2] + s0[3]);
        float a1 = (s0[4] + s0[5]) + (s0[6] + s0[7]);
        float a2 = (s0[8] + s0[9]) + (s0[10] + s0[11]);
        float a3 = (s0[12] + s0[13]) + (s0[14] + s0[15]);
        float ps = (a0 + a1) + (a2 + a3);
        if (MODE != 2) {
            float b0 = (s1[0] + s1[1]) + (s1[2] + s1[3]);
            float b1 = (s1[4] + s1[5]) + (s1[6] + s1[7]);
            float b2 = (s1[8] + s1[9]) + (s1[10] + s1[11]);
            float b3 = (s1[12] + s1[13]) + (s1[14] + s1[15]);
            ps += (b0 + b1) + (b2 + b3);
        }
        lsum += ps;
    }

#pragma unroll
    for (int c = 0; c < (MODE == 2 ? 1 : 2); ++c) {
#pragma unroll
        for (int u2 = 0; u2 < 2; ++u2) {
            const int u = c * 2 + u2;
            bf16x8 pb;
#pragma unroll
            for (int j = 0; j < 8; ++j) pb[j] = (bf16)(c ? s1[u2 * 8 + j] : s0[u2 * 8 + j]);
#pragma unroll
            for (int dt = 0; dt < 2; ++dt) {
                bf16x8 va = *reinterpret_cast<const bf16x8*>(
                    &Vlb[(dt * 32 + ql) * 64 + (((u * 2 + hi) ^ swq) * 8)]);
                o[dt] = __builtin_amdgcn_mfma_f32_32x32x16_bf16(va, pb, o[dt], 0, 0, 0);
            }
        }
    }
}

__global__ __launch_bounds__(256, 3) void attn(
    const bf16* __restrict__ Qb, const bf16* __restrict__ Kb, const bf16* __restrict__ Vt,
    bf16* __restrict__ Ab)
{
    __shared__ bf16 Kl[3][64 * 64];
    __shared__ bf16 Vl[3][64 * 64];

    const int bh = blockIdx.x;
    const int qt = (int)gridDim.y - 1 - (int)blockIdx.y;   // longest tiles launch first (LPT)
    const int t = threadIdx.x, w = t >> 6, l = t & 63;
    const int ql = l & 31, hi = l >> 5;
    const int q0 = qt * 128 + w * 32;
    const bf16* Qh = Qb + (size_t)bh * SEQ * DK;
    const bf16* Kh = Kb + (size_t)bh * SEQ * DK;
    const bf16* Vh = Vt + (size_t)bh * DK * SEQ;

    const int lr = l >> 3, slot = l & 7;
    const int sw8 = ((slot ^ lr) * 8);
    const int r0 = w * 8 + lr;

    auto stage = [&](int tile, int buf) {
        const int kv0 = tile * 64;
        GLOAD_LDS16(Kh + (size_t)(kv0 + r0) * DK + sw8,       &Kl[buf][w * 512]);
        GLOAD_LDS16(Kh + (size_t)(kv0 + 32 + r0) * DK + sw8,  &Kl[buf][2048 + w * 512]);
        GLOAD_LDS16(Vh + (size_t)r0 * SEQ + kv0 + sw8,        &Vl[buf][w * 512]);
        GLOAD_LDS16(Vh + (size_t)(32 + r0) * SEQ + kv0 + sw8, &Vl[buf][2048 + w * 512]);
    };

    bf16x8 qb[4];
#pragma unroll
    for (int sl = 0; sl < 4; ++sl)
        qb[sl] = *reinterpret_cast<const bf16x8*>(Qh + (size_t)(q0 + ql) * DK + sl * 16 + hi * 8);

    f32x16 o[2] = {};
    float lsum = 0.0f;
    float mrow = -1e30f;
    const int q_abs = q0 + ql;
    const int swq = ql & 7;

    const int ntile = 2 * qt + 2;   // always >= 2
    stage(0, 0);
    stage(1, 1);
    PIPE_WAIT(4);                   // tile0 landed; tile1 in flight
    for (int tt = 0; tt < ntile; ++tt) {
        if (tt + 2 < ntile) stage(tt + 2, (tt + 2) % 3);
        const int kv0 = tt * 64;
        const bf16* Klb = &Kl[tt % 3][0];
        const bf16* Vlb = &Vl[tt % 3][0];
        if (tt < 2 * qt) {
            tileproc<0>(Klb, Vlb, kv0, q_abs, ql, hi, swq, qb, o, lsum, mrow);
        } else {
            const bool a0 = kv0 <= q0 + 31;
            const bool a1 = kv0 + 32 <= q0 + 31;
            if (a1)      tileproc<1>(Klb, Vlb, kv0, q_abs, ql, hi, swq, qb, o, lsum, mrow);
            else if (a0) tileproc<2>(Klb, Vlb, kv0, q_abs, ql, hi, swq, qb, o, lsum, mrow);
        }
        if (tt + 1 < ntile) {
            if (tt + 2 < ntile) PIPE_WAIT(4);   // t+1 landed; t+2 in flight
            else               PIPE_WAIT(0);    // only t+1 outstanding
        }
        // tt == ntile-1: fall through to epilogue
    }

    const float rs = lsum + __shfl_xor(lsum, 32);
    const float rinv = 1.0f / rs;

    const int b = bh >> 4, h = bh & 15;
    const int q = q0 + ql;
    const size_t rowbase = ((size_t)(b * SEQ + q)) * DMODEL + h * 64;
#pragma unroll
    for (int dt = 0; dt < 2; ++dt)
#pragma unroll
        for (int g = 0; g < 4; ++g) {
            bf16x4 v4;
#pragma unroll
            for (int e = 0; e < 4; ++e) v4[e] = (bf16)(o[dt][4 * g + e] * rinv);
            *reinterpret_cast<bf16x4*>(Ab + rowbase + dt * 32 + 8 * g + 4 * hi) = v4;
        }
}

// ---------------- output GEMM (C^T = Wo Ab^T), 8-wave depth-2 pipeline (R13) ------
__global__ __launch_bounds__(512, 2) void gemm_out(
    const bf16* __restrict__ Ab, const bf16* __restrict__ Wob, float* __restrict__ Out)
{
    __shared__ bf16 Wl[3][128 * 64];
    __shared__ bf16 Xl[3][256 * 64];

    // T1 bijective swizzle: 256 blocks = 8 XCDs x 32
    const int bid = (int)blockIdx.x;
    const int swz = (bid & 7) * 32 + (bid >> 3);
    const int ytile = swz >> 3;          // s-tile 0..31
    const int xtile = swz & 7;           // n-tile 0..7

    const int n0 = xtile * 128;          // output-channel tile
    const int s0 = ytile * 256;          // token-row tile
    const int t = threadIdx.x;
    const int w = t >> 6, l = t & 63;
    const int wd = w >> 2, wq = w & 3;
    const int lm = l & 15, lg = l >> 4;
    const int lm7 = lm & 7;

    f32x4 acc[4][4] = {};   // [fi (n)][fj (s)]

    auto stageW = [&](int kt, int buf) {
#pragma unroll
        for (int j = 0; j < 2; ++j) {
            const int slot = w * 64 + j * 512 + l;
            const int row = slot >> 3;
            const int col = ((slot & 7) ^ (row & 7)) * 8;
            GLOAD_LDS16(Wob + (size_t)(n0 + row) * KDIM + kt + col,
                        &Wl[buf][(w * 64 + j * 512) * 8]);
        }
    };
    auto stageX = [&](int kt, int buf) {
#pragma unroll
        for (int j = 0; j < 4; ++j) {
            const int slot = w * 64 + j * 512 + l;
            const int row = slot >> 3;
            const int col = ((slot & 7) ^ (row & 7)) * 8;
            GLOAD_LDS16(Ab + (size_t)(s0 + row) * KDIM + kt + col,
                        &Xl[buf][(w * 64 + j * 512) * 8]);
        }
    };
    auto compute = [&](const bf16* Wb, const bf16* Xq) {
        bf16x8 wf[4][2], xf[4][2];
#pragma unroll
        for (int fi = 0; fi < 4; ++fi) {
            const int row = wd * 64 + fi * 16 + lm;
#pragma unroll
            for (int kk = 0; kk < 2; ++kk)
                wf[fi][kk] = *reinterpret_cast<const bf16x8*>(
                    Wb + row * 64 + (((kk * 4 + lg) ^ lm7) * 8));
        }
#pragma unroll
        for (int fj = 0; fj < 4; ++fj) {
            const int row = wq * 64 + fj * 16 + lm;
#pragma unroll
            for (int kk = 0; kk < 2; ++kk)
                xf[fj][kk] = *reinterpret_cast<const bf16x8*>(
                    Xq + row * 64 + (((kk * 4 + lg) ^ lm7) * 8));
        }
        __builtin_amdgcn_s_setprio(1);
#pragma unroll
        for (int kk = 0; kk < 2; ++kk)
#pragma unroll
            for (int fi = 0; fi < 4; ++fi)
#pragma unroll
                for (int fj = 0; fj < 4; ++fj)
                    acc[fi][fj] = __builtin_amdgcn_mfma_f32_16x16x32_bf16(
                        wf[fi][kk], xf[fj][kk], acc[fi][fj], 0, 0, 0);
        __builtin_amdgcn_s_setprio(0);
    };

    stageW(0, 0);
    stageX(0, 0);
    stageW(64, 1);
    stageX(64, 1);
    PIPE_WAIT(6);

#pragma unroll
    for (int tt = 0; tt < 16; ++tt) {
        if (tt + 2 < 16) {
            stageW((tt + 2) * 64, (tt + 2) % 3);
            stageX((tt + 2) * 64, (tt + 2) % 3);
        }
        compute(&Wl[tt % 3][0], &Xl[tt % 3][0]);
        if (tt < 14)       PIPE_WAIT(6);
        else if (tt == 14) PIPE_WAIT(0);
    }

#pragma unroll
    for (int fj = 0; fj < 4; ++fj) {
        const int rowg = s0 + wq * 64 + fj * 16 + lm;
#pragma unroll
        for (int fi = 0; fi < 4; ++fi) {
            const int ncol = n0 + wd * 64 + fi * 16 + lg * 4;
            *reinterpret_cast<f32x4*>(Out + (size_t)rowg * DMODEL + ncol) = acc[fi][fj];
        }
    }
}

// ---------------- launch ----------------
extern "C" void kernel_launch(void* const* d_in, const int* in_sizes, int n_in,
                              void* d_out, int out_size, void* d_ws, size_t ws_size,
                              hipStream_t stream) {
    const float* X  = (const float*)d_in[0];
    const int* tokpos = (const int*)d_in[1];
    const float* Wq = (const float*)d_in[2];
    const float* Wk = (const float*)d_in[3];
    const float* Wv = (const float*)d_in[4];
    const float* Wo = (const float*)d_in[5];

    char* ws = (char*)d_ws;
    bf16* Xb  = (bf16*)(ws + 0);            // 16 MB
    bf16* Wqb = (bf16*)(ws + 16777216);     // 2 MB
    bf16* Wkb = (bf16*)(ws + 18874368);
    bf16* Wvb = (bf16*)(ws + 20971520);
    bf16* Wob = (bf16*)(ws + 23068672);
    float2* csT = (float2*)(ws + 25165824); // 512 KB interleaved (cos,sin)
    bf16* Qb = (bf16*)(ws + 25690112);      // 16 MB
    bf16* Kb = (bf16*)(ws + 42467328);
    bf16* Vt = (bf16*)(ws + 59244544);      // 16 MB (V^T, sigma-permuted)
    bf16* Ab = (bf16*)(ws + 76021760);      // 16 MB

    prep<<<6400, 256, 0, stream>>>(X, Wq, Wk, Wv, Wo, Xb, Wqb, Wkb, Wvb, Wob, csT);

    gemm_qkv<<<dim3(768), 512, 0, stream>>>(
        Xb, Wqb, Wkb, Wvb, Qb, Kb, Vt, tokpos, csT);

    attn<<<dim3(BATCH * NH, SEQ / 128), 256, 0, stream>>>(Qb, Kb, Vt, Ab);

    gemm_out<<<dim3(256), 512, 0, stream>>>(Ab, Wob, (float*)d_out);
}